// Round 1
// baseline (80.563 us; speedup 1.0000x reference)
//
#include <hip/hip_runtime.h>

// RPNPooling: B=2, H=128, W=128, C=256, N=512, POOL=14
// out[q,i,j,ch], q in [0,1024), i,j in [0,14), ch in [0,256)
// Reference quirk: r-axis (feature H index) derives from roi x-coords,
// c-axis (feature W index) derives from roi y-coords. Replicated verbatim.

#define NCELL (1024 * 14 * 14)   // 200704
#define CELLS_PER_BLOCK 4

__global__ __launch_bounds__(256) void rpn_pool_kernel(
    const float* __restrict__ feat,   // [2,128,128,256]
    const int*   __restrict__ roi,    // [1024,4] = y1,x1,y2,x2
    float*       __restrict__ out)    // [1024,14,14,256]
{
    const int lane = threadIdx.x & 63;
    const int cell = blockIdx.x * CELLS_PER_BLOCK + (threadIdx.x >> 6);
    if (cell >= NCELL) return;

    const int q  = cell / 196;        // roi index
    const int ij = cell - q * 196;
    const int i  = ij / 14;
    const int j  = ij - i * 14;
    const int b  = q >> 9;            // q / N, N=512

    const int4 rr = ((const int4*)roi)[q];
    const int y1 = rr.x, x1 = rr.y, y2 = rr.z, x2 = rr.w;

    // r-axis (H) from x coords, c-axis (W) from y coords (reference swap)
    const int sR = x2 - x1;
    const int sC = y2 - y1;

    const int pr  = i * sR;
    const int ir0 = pr / 14;
    const float fr = (float)(pr - ir0 * 14) * (1.0f / 14.0f);
    const int r0 = x1 + ir0;
    const int r1 = x1 + min(ir0 + 1, sR - 1);

    const int pc  = j * sC;
    const int ic0 = pc / 14;
    const float fc = (float)(pc - ic0 * 14) * (1.0f / 14.0f);
    const int c0 = y1 + ic0;
    const int c1 = y1 + min(ic0 + 1, sC - 1);

    const size_t SB = (size_t)128 * 128 * 256;
    const size_t SR = (size_t)128 * 256;
    const size_t SC = 256;

    const float* base = feat + (size_t)b * SB;
    const float4* p00 = (const float4*)(base + (size_t)r0 * SR + (size_t)c0 * SC) + lane;
    const float4* p01 = (const float4*)(base + (size_t)r0 * SR + (size_t)c1 * SC) + lane;
    const float4* p10 = (const float4*)(base + (size_t)r1 * SR + (size_t)c0 * SC) + lane;
    const float4* p11 = (const float4*)(base + (size_t)r1 * SR + (size_t)c1 * SC) + lane;

    const float4 g00 = *p00;
    const float4 g01 = *p01;
    const float4 g10 = *p10;
    const float4 g11 = *p11;

    const float wc1 = 1.0f - fc, wc = fc;
    const float wr1 = 1.0f - fr, wr = fr;

    float4 o;
    o.x = (g00.x * wc1 + g01.x * wc) * wr1 + (g10.x * wc1 + g11.x * wc) * wr;
    o.y = (g00.y * wc1 + g01.y * wc) * wr1 + (g10.y * wc1 + g11.y * wc) * wr;
    o.z = (g00.z * wc1 + g01.z * wc) * wr1 + (g10.z * wc1 + g11.z * wc) * wr;
    o.w = (g00.w * wc1 + g01.w * wc) * wr1 + (g10.w * wc1 + g11.w * wc) * wr;

    ((float4*)out)[(size_t)cell * 64 + lane] = o;
}

extern "C" void kernel_launch(void* const* d_in, const int* in_sizes, int n_in,
                              void* d_out, int out_size, void* d_ws, size_t ws_size,
                              hipStream_t stream) {
    const float* feat = (const float*)d_in[0];
    const int*   roi  = (const int*)d_in[1];
    float* out = (float*)d_out;

    const int nblocks = NCELL / CELLS_PER_BLOCK;   // 50176
    rpn_pool_kernel<<<nblocks, 256, 0, stream>>>(feat, roi, out);
}

// Round 3
// 53.524 us; speedup vs baseline: 1.5052x; 1.5052x over previous
//
#include <hip/hip_runtime.h>

// RPNPooling: B=2, H=128, W=128, C=256, N=512, POOL=14
// out[q,i,j,ch], q in [0,1024), i,j in [0,14), ch in [0,256)
// Reference quirk: r-axis (feature H index) derives from roi x-coords,
// c-axis (feature W index) derives from roi y-coords. Replicated verbatim.
//
// R2 = R1 with native ext_vector_type for the nontemporal store
// (HIP float4 is a class type and __builtin_nontemporal_store rejects it).

typedef float f32x4 __attribute__((ext_vector_type(4)));

#define NROI 1024
#define CMAX 15          // roi span is in [8,15]
#define THREADS 448      // 7 waves -> 2 cells per wave, balanced
#define NWG (NROI * 14)  // 14336
#define WG_PER_XCD (NWG / 8)  // 1792

__global__ __launch_bounds__(THREADS) void rpn_pool_kernel(
    const float* __restrict__ feat,   // [2,128,128,256]
    const int*   __restrict__ roi,    // [1024,4] = y1,x1,y2,x2
    float*       __restrict__ out)    // [1024,14,14,256]
{
    __shared__ float lds[2][CMAX][256];   // 30 KB

    // XCD-aware swizzle (bijective: NWG % 8 == 0): XCD k owns ROIs [k*128,(k+1)*128),
    // rows i of one ROI temporally adjacent on the same XCD.
    const int d = blockIdx.x;
    const int w = (d & 7) * WG_PER_XCD + (d >> 3);
    const int q = w / 14;
    const int i = w - q * 14;
    const int b = q >> 9;             // q / 512

    const int4 rr = ((const int4*)roi)[q];
    const int y1 = rr.x, x1 = rr.y, y2 = rr.z, x2 = rr.w;

    const int sR = x2 - x1;           // H-extent from x coords (reference swap)
    const int sC = y2 - y1;           // W-extent from y coords

    const int pr  = i * sR;
    const int ir0 = pr / 14;
    const float fr = (float)(pr - ir0 * 14) * (1.0f / 14.0f);
    const int r0 = x1 + ir0;
    const int r1 = x1 + min(ir0 + 1, sR - 1);

    const size_t SB = (size_t)128 * 128 * 256;
    const size_t SR = (size_t)128 * 256;

    const float* base = feat + (size_t)b * SB;
    const f32x4* row0 = (const f32x4*)(base + (size_t)r0 * SR + (size_t)y1 * 256);
    const f32x4* row1 = (const f32x4*)(base + (size_t)r1 * SR + (size_t)y1 * 256);

    // Stage two contiguous row segments (sC * 1KB each) into LDS.
    const int rowElems = sC * 64;     // f32x4 count per row
    f32x4* lds4 = (f32x4*)lds;
    for (int idx = threadIdx.x; idx < rowElems; idx += THREADS)
        lds4[idx] = row0[idx];
    for (int idx = threadIdx.x; idx < rowElems; idx += THREADS)
        lds4[CMAX * 64 + idx] = row1[idx];
    __syncthreads();

    const int wave = threadIdx.x >> 6;
    const int lane = threadIdx.x & 63;
    const float wr1 = 1.0f - fr;

    for (int j = wave; j < 14; j += 7) {
        const int pc  = j * sC;
        const int ic0 = pc / 14;
        const float fc = (float)(pc - ic0 * 14) * (1.0f / 14.0f);
        const int c0 = ic0;                 // local column index in LDS
        const int c1 = min(ic0 + 1, sC - 1);
        const float wc1 = 1.0f - fc;

        const f32x4 g00 = ((const f32x4*)lds[0][c0])[lane];
        const f32x4 g01 = ((const f32x4*)lds[0][c1])[lane];
        const f32x4 g10 = ((const f32x4*)lds[1][c0])[lane];
        const f32x4 g11 = ((const f32x4*)lds[1][c1])[lane];

        f32x4 o = (g00 * wc1 + g01 * fc) * wr1 + (g10 * wc1 + g11 * fc) * fr;

        const size_t oidx = ((size_t)q * 196 + (size_t)i * 14 + j) * 64 + lane;
        __builtin_nontemporal_store(o, ((f32x4*)out) + oidx);
    }
}

extern "C" void kernel_launch(void* const* d_in, const int* in_sizes, int n_in,
                              void* d_out, int out_size, void* d_ws, size_t ws_size,
                              hipStream_t stream) {
    const float* feat = (const float*)d_in[0];
    const int*   roi  = (const int*)d_in[1];
    float* out = (float*)d_out;

    rpn_pool_kernel<<<NWG, THREADS, 0, stream>>>(feat, roi, out);
}